// Round 1
// baseline (265.558 us; speedup 1.0000x reference)
//
#include <hip/hip_runtime.h>
#include <math.h>

// SpatialSampler: B=256, A=64, k=64, P=32, BETA=0.1
//   places[b,p,j,k]        = h[b,p,j] * v[b,p,k]
//   sampled_points[b,p,j,k]= 100 * h[jmax]*v[kmax] at (jmax,kmax) else 0
// where jmax = argmax_j log(h[j]) + BETA*noise_h[j] (same for v).
// Output: [places (33.55M floats) | sampled_points (33.55M floats)].
// Store-BW bound: 268 MB writes, 8 MB reads.

#define BETA 0.1f
#define PLACES_ELEMS 33554432ull   // 256*32*64*64

__global__ __launch_bounds__(256) void spatial_sampler_kernel(
    const float* __restrict__ x_cat,
    const float* __restrict__ noise,
    float* __restrict__ out)
{
    // One block per (b,p): bp = b*32+p in [0,8192)
    const int bp   = blockIdx.x;
    const int t    = threadIdx.x;
    const int wave = t >> 6;
    const int lane = t & 63;

    // x_cat[b, 2p + s, j] -> flat b*4096 + 128*p + s*64 + j = bp*128 + s*64 + j
    const float* xrow = x_cat + (size_t)bp * 128;
    const float* nrow = noise + (size_t)bp * 128;

    __shared__ float sh[64];
    __shared__ float sv[64];
    __shared__ int   s_max[2];   // [0]=jmax (h), [1]=kmax (v)

    if (wave < 2) {
        // wave 0 -> h (s=0), wave 1 -> v (s=1)
        const int base = wave * 64;
        float x = xrow[base + lane];
        if (wave == 0) sh[lane] = x; else sv[lane] = x;

        float lp  = logf(x) + BETA * nrow[base + lane];
        int   idx = lane;
        #pragma unroll
        for (int off = 32; off > 0; off >>= 1) {
            float o_lp  = __shfl_xor(lp, off, 64);
            int   o_idx = __shfl_xor(idx, off, 64);
            if (o_lp > lp || (o_lp == lp && o_idx < idx)) { lp = o_lp; idx = o_idx; }
        }
        if (lane == 0) s_max[wave] = idx;
    }
    __syncthreads();

    const int jmax = s_max[0];
    const int kmax = s_max[1];

    // Each (b,p) owns 4096 floats = 1024 float4 per output tensor.
    float4* __restrict__ places  = (float4*)out + (size_t)bp * 1024;
    float4* __restrict__ sampled = (float4*)(out + PLACES_ELEMS) + (size_t)bp * 1024;

    #pragma unroll
    for (int i = 0; i < 4; ++i) {
        const int f = i * 256 + t;     // float4 index in [0,1024): coalesced
        const int j = f >> 4;          // row (0..63)
        const int c = (f & 15) << 2;   // col base (0,4,...,60)

        const float hj = sh[j];
        float4 p;
        p.x = hj * sv[c + 0];
        p.y = hj * sv[c + 1];
        p.z = hj * sv[c + 2];
        p.w = hj * sv[c + 3];
        places[f] = p;

        float4 sp = make_float4(0.f, 0.f, 0.f, 0.f);
        if (j == jmax) {
            if (c + 0 == kmax) sp.x = p.x * 100.f;
            if (c + 1 == kmax) sp.y = p.y * 100.f;
            if (c + 2 == kmax) sp.z = p.z * 100.f;
            if (c + 3 == kmax) sp.w = p.w * 100.f;
        }
        sampled[f] = sp;
    }
}

extern "C" void kernel_launch(void* const* d_in, const int* in_sizes, int n_in,
                              void* d_out, int out_size, void* d_ws, size_t ws_size,
                              hipStream_t stream) {
    const float* x_cat = (const float*)d_in[0];
    const float* noise = (const float*)d_in[1];
    float* out = (float*)d_out;

    // 256*32 = 8192 (b,p) pairs, one block each.
    spatial_sampler_kernel<<<dim3(8192), dim3(256), 0, stream>>>(x_cat, noise, out);
}